// Round 4
// baseline (341.829 us; speedup 1.0000x reference)
//
#include <hip/hip_runtime.h>
#include <math.h>

// n=16384 Gaussian points in 3D. Exact 12-NN (incl self) per point:
//   out[i] = b + ( (W·p_i)·(1 + 11/sqrt(2)) + 0.5 * sum_{11NN} W·|p_i - p_j| ) / 12
//
// R4: bin-sort by x (K1-K3). K4: 2048 single-wave blocks, 8 consecutive sorted
// queries x 8 slices each. Adaptive window expansion with EXACT per-query tau
// (8-way merge every round) as the stop bound:
//   (x-gap to unstaged side - binwidth)^2 > max_q tau12_q  -> side done.
// Exact: all points within sqrt(tau_final) of any query are staged.
// Phase 2 rescans final window with exact tau; self contributes 0.

#define NBINS   2048
#define XMIN_   (-6.0f)
#define XRANGE_ (12.0f)
#define BW_     (XRANGE_ / (float)NBINS)
#define INVBW_  ((float)NBINS / XRANGE_)
#define SLACK_  (BW_ * 1.02f)
#define TILE    512
#define HALF    256
#define GL      8
#define QPB     8
#define BLOCK   64
#define KK      12
#define KP      13          // padded stride for s_d (kills 12-stride bank conflicts)
#define BIG     3.0e38f
#define PADX    1.0e30f

__device__ __forceinline__ int bin_of(float x) {
  int b = (int)((x - XMIN_) * INVBW_);
  b = b < 0 ? 0 : b;
  b = b > NBINS - 1 ? NBINS - 1 : b;
  return b;
}

// ---------------- K1: histogram ----------------
__global__ void hist_kernel(const float* __restrict__ p, int* __restrict__ hist, int n) {
  const int i = blockIdx.x * blockDim.x + threadIdx.x;
  if (i < n) atomicAdd(&hist[bin_of(p[3 * i])], 1);
}

// ---------------- K2: exclusive prefix scan ----------------
__global__ __launch_bounds__(256)
void scan_kernel(const int* __restrict__ hist, int* __restrict__ cursor) {
  __shared__ int s[256];
  const int tid = threadIdx.x;
  const int base = tid * (NBINS / 256);
  int v[NBINS / 256];
  int sum = 0;
#pragma unroll
  for (int t = 0; t < NBINS / 256; ++t) { v[t] = hist[base + t]; sum += v[t]; }
  s[tid] = sum;
  __syncthreads();
#pragma unroll
  for (int off = 1; off < 256; off <<= 1) {
    int x = (tid >= off) ? s[tid - off] : 0;
    __syncthreads();
    s[tid] += x;
    __syncthreads();
  }
  int run = (tid > 0) ? s[tid - 1] : 0;
#pragma unroll
  for (int t = 0; t < NBINS / 256; ++t) { cursor[base + t] = run; run += v[t]; }
}

// ---------------- K3: scatter into bin-sorted float4 array -------------------
__global__ void scatter_kernel(const float* __restrict__ p, int* __restrict__ cursor,
                               float4* __restrict__ sorted, int n) {
  const int i = blockIdx.x * blockDim.x + threadIdx.x;
  if (i < n) {
    const float x = p[3 * i + 0];
    const float y = p[3 * i + 1];
    const float z = p[3 * i + 2];
    const int pos = atomicAdd(&cursor[bin_of(x)], 1);
    sorted[pos] = make_float4(x, y, z, __int_as_float(i));
  }
}

// ---------------- K4: query (single-wave blocks) ------------------------------
__global__ __launch_bounds__(BLOCK)
void query_kernel(const float4* __restrict__ sv, const float* __restrict__ W,
                  const float* __restrict__ bias, float* __restrict__ out, int n) {
  __shared__ __align__(16) float s_x[TILE];
  __shared__ __align__(16) float s_y[TILE];
  __shared__ __align__(16) float s_z[TILE];
  __shared__ float s_d[BLOCK * KP];
  __shared__ float s_tau[QPB];
  __shared__ float s_q[QPB];

  const int tid = threadIdx.x;
  const int sl  = tid & (GL - 1);
  const int ql  = tid >> 3;
  const int t   = blockIdx.x * QPB + ql;          // this query's sorted position
  const int cb0 = blockIdx.x * QPB + (QPB / 2);   // window center

  const float4 me = sv[t];
  const float xi = me.x, yi = me.y, zi = me.z;
  const int orig = __float_as_int(me.w);

  if (sl == 0) s_q[ql] = xi;
  __syncthreads();
  float xmn = s_q[0], xmx = s_q[0];
#pragma unroll
  for (int k = 1; k < QPB; ++k) { xmn = fminf(xmn, s_q[k]); xmx = fmaxf(xmx, s_q[k]); }

  float dist[KK];
#pragma unroll
  for (int k = 0; k < KK; ++k) dist[k] = BIG;

  int rlo = cb0 - HALF;            // staged extent [rlo, rhi), unclamped
  int rhi = cb0 + HALF;
  int ldone = 0, rdone = 0;

  // initial staging: [rlo, rhi) -> slots [0, TILE)
#pragma unroll
  for (int j0 = 0; j0 < TILE; j0 += BLOCK) {
    const int j = j0 + tid;
    const int pos = rlo + j;
    const bool v = (pos >= 0) && (pos < n);
    const float4 cc = v ? sv[pos] : make_float4(PADX, PADX, PADX, 0.f);
    s_x[j] = cc.x; s_y[j] = cc.y; s_z[j] = cc.z;
  }
  __syncthreads();
  float xl = s_x[0];
  float xr = s_x[TILE - 1];

  for (;;) {
    // ---- eval fresh tile: branch-free med3 top-12 insert ----
#pragma unroll 2
    for (int g = sl; g < TILE / 4; g += GL) {
      const int cbs = g * 4;
      const float4 X = *(const float4*)&s_x[cbs];
      const float4 Y = *(const float4*)&s_y[cbs];
      const float4 Z = *(const float4*)&s_z[cbs];
      float d2v[4];
      { const float dx = xi - X.x, dy = yi - Y.x, dz = zi - Z.x; d2v[0] = dx*dx + dy*dy + dz*dz; }
      { const float dx = xi - X.y, dy = yi - Y.y, dz = zi - Z.y; d2v[1] = dx*dx + dy*dy + dz*dz; }
      { const float dx = xi - X.z, dy = yi - Y.z, dz = zi - Z.z; d2v[2] = dx*dx + dy*dy + dz*dz; }
      { const float dx = xi - X.w, dy = yi - Y.w, dz = zi - Z.w; d2v[3] = dx*dx + dy*dy + dz*dz; }
#pragma unroll
      for (int e = 0; e < 4; ++e) {
        const float d = d2v[e];
#pragma unroll
        for (int k = KK - 1; k >= 1; --k)
          dist[k] = __builtin_amdgcn_fmed3f(d, dist[k - 1], dist[k]);
        dist[0] = fminf(dist[0], d);
      }
    }

    // ---- exact per-query tau (8-way merge of sorted lists) ----
    __syncthreads();
#pragma unroll
    for (int k = 0; k < KK; ++k) s_d[tid * KP + k] = dist[k];
    __syncthreads();
    if (sl == 0) {
      int h[GL];
#pragma unroll
      for (int g = 0; g < GL; ++g) h[g] = 0;
      float tau = 0.f;
      for (int r = 0; r < KK; ++r) {
        float best = 3.4e38f; int bs = 0;
#pragma unroll
        for (int g = 0; g < GL; ++g) {
          const float v = s_d[(tid + g) * KP + h[g]];
          if (v < best) { best = v; bs = g; }
        }
#pragma unroll
        for (int g = 0; g < GL; ++g) h[g] += (bs == g) ? 1 : 0;
        tau = best;
      }
      s_tau[ql] = tau;
    }
    __syncthreads();
    float bt = s_tau[0];
#pragma unroll
    for (int k = 1; k < QPB; ++k) bt = fmaxf(bt, s_tau[k]);

    // ---- stop tests (uniform, no serialization) ----
    if (!ldone) {
      if (rlo <= 0) ldone = 1;
      else {
        const float g = xmn - xl - SLACK_;
        ldone = (g > 0.f && g * g > bt) ? 1 : 0;
      }
    }
    if (!rdone) {
      if (rhi >= n) rdone = 1;
      else {
        const float g = xr - SLACK_ - xmx;
        rdone = (g > 0.f && g * g > bt) ? 1 : 0;
      }
    }
    if (ldone && rdone) break;

    // ---- stage next ring; a finished side donates its half to the other ----
    const int lc = ldone ? 0 : (rdone ? TILE : HALF);   // left entries
    __syncthreads();
#pragma unroll
    for (int j0 = 0; j0 < TILE; j0 += BLOCK) {
      const int j = j0 + tid;
      float4 cc;
      if (j < lc) {
        const int pos = rlo - lc + j;
        cc = (pos >= 0) ? sv[pos] : make_float4(PADX, PADX, PADX, 0.f);
      } else {
        const int pos = rhi + (j - lc);
        cc = (pos < n && !rdone) ? sv[pos] : make_float4(PADX, PADX, PADX, 0.f);
      }
      s_x[j] = cc.x; s_y[j] = cc.y; s_z[j] = cc.z;
    }
    rlo -= lc;
    if (!rdone) rhi += TILE - lc;
    __syncthreads();
    xl = s_x[0];
    xr = s_x[TILE - 1];
  }

  // ---- phase 2: rescan final window with exact tau ----
  const float tau = s_tau[ql];
  const float W0 = W[0], W1 = W[1], W2 = W[2];
  const int lo0 = rlo > 0 ? rlo : 0;
  const int hi0 = rhi < n ? rhi : n;
  float acc = 0.f;
  for (int s = lo0; s < hi0; s += TILE) {
    __syncthreads();
#pragma unroll
    for (int j0 = 0; j0 < TILE; j0 += BLOCK) {
      const int j = j0 + tid;
      const int pos = s + j;
      const bool v = (pos < hi0);
      const float4 cc = v ? sv[pos] : make_float4(PADX, PADX, PADX, 0.f);
      s_x[j] = cc.x; s_y[j] = cc.y; s_z[j] = cc.z;
    }
    __syncthreads();
#pragma unroll 2
    for (int g = sl; g < TILE / 4; g += GL) {
      const int cbs = g * 4;
      const float4 X = *(const float4*)&s_x[cbs];
      const float4 Y = *(const float4*)&s_y[cbs];
      const float4 Z = *(const float4*)&s_z[cbs];
      {
        const float dx = xi - X.x, dy = yi - Y.x, dz = zi - Z.x;
        const float d2 = dx*dx + dy*dy + dz*dz;
        acc += (d2 <= tau) ? (W0 * fabsf(dx) + W1 * fabsf(dy) + W2 * fabsf(dz)) : 0.f;
      }
      {
        const float dx = xi - X.y, dy = yi - Y.y, dz = zi - Z.y;
        const float d2 = dx*dx + dy*dy + dz*dz;
        acc += (d2 <= tau) ? (W0 * fabsf(dx) + W1 * fabsf(dy) + W2 * fabsf(dz)) : 0.f;
      }
      {
        const float dx = xi - X.z, dy = yi - Y.z, dz = zi - Z.z;
        const float d2 = dx*dx + dy*dy + dz*dz;
        acc += (d2 <= tau) ? (W0 * fabsf(dx) + W1 * fabsf(dy) + W2 * fabsf(dz)) : 0.f;
      }
      {
        const float dx = xi - X.w, dy = yi - Y.w, dz = zi - Z.w;
        const float d2 = dx*dx + dy*dy + dz*dz;
        acc += (d2 <= tau) ? (W0 * fabsf(dx) + W1 * fabsf(dy) + W2 * fabsf(dz)) : 0.f;
      }
    }
  }

  // ---- reduce over the 8 slice lanes (contiguous in the wave) ----
  acc += __shfl_xor(acc, 1);
  acc += __shfl_xor(acc, 2);
  acc += __shfl_xor(acc, 4);
  if (sl == 0) {
    const float xw0 = W0 * xi + W1 * yi + W2 * zi;
    out[orig] = bias[0] + (xw0 * 8.778174593052022f + 0.5f * acc) * (1.0f / 12.0f);
  }
}

extern "C" void kernel_launch(void* const* d_in, const int* in_sizes, int n_in,
                              void* d_out, int out_size, void* d_ws, size_t ws_size,
                              hipStream_t stream) {
  const float* p  = (const float*)d_in[0];
  const float* W  = (const float*)d_in[1];
  const float* bb = (const float*)d_in[2];
  float* out = (float*)d_out;

  const int n = in_sizes[0] / 3;   // 16384

  int*    hist   = (int*)d_ws;
  int*    cursor = (int*)((char*)d_ws + NBINS * 4);
  float4* sorted = (float4*)((char*)d_ws + 2 * NBINS * 4);

  hipMemsetAsync(hist, 0, NBINS * 4, stream);

  const int b256 = (n + 255) / 256;
  hist_kernel<<<b256, 256, 0, stream>>>(p, hist, n);
  scan_kernel<<<1, 256, 0, stream>>>(hist, cursor);
  scatter_kernel<<<b256, 256, 0, stream>>>(p, cursor, sorted, n);
  query_kernel<<<n / QPB, BLOCK, 0, stream>>>(sorted, W, bb, out, n);
}